// Round 11
// baseline (2660.619 us; speedup 1.0000x reference)
//
#include <hip/hip_runtime.h>
#include <math.h>

#define BSZ 64
#define TLEN 256
#define LSND 65536
#define ZK 160            // z K-length in bf16 slots: 129 real + iv-residual@129 + pads

typedef __attribute__((ext_vector_type(8))) short bf16x8;
typedef __attribute__((ext_vector_type(4))) float f32x4;

__device__ __forceinline__ float sigm(float x) { return 1.f / (1.f + __expf(-x)); }
__device__ __forceinline__ float tanh_f(float x) {
  float e = __expf(-2.f * fabsf(x));
  return copysignf((1.f - e) / (1.f + e), x);
}
__device__ __forceinline__ unsigned short f2bf(float x) {   // RNE f32->bf16
  unsigned u = __float_as_uint(x);
  return (unsigned short)((u + 0x7FFFu + ((u >> 16) & 1u)) >> 16);
}
__device__ __forceinline__ f32x4 unpack4(unsigned long long v) {
  f32x4 r;
  r[0] = __uint_as_float((unsigned)(v & 0xFFFFu) << 16);
  r[1] = __uint_as_float((unsigned)((v >> 16) & 0xFFFFu) << 16);
  r[2] = __uint_as_float((unsigned)((v >> 32) & 0xFFFFu) << 16);
  r[3] = __uint_as_float((unsigned)((v >> 48) & 0xFFFFu) << 16);
  return r;
}
// weight-row permutation: tile row m -> (jl=m>>2, gate=m&3); n = gate*256 + q*4 + jl
__device__ __forceinline__ int nrow(int q, int m) {
  return ((m & 3) << 8) + (q << 2) + (m >> 2);
}

// K1: fold linear into w_ih: Wc[n][j] (1024x132, cols>=129 zero); bc = folded bias
__global__ __launch_bounds__(256) void prep_kernel(
    const float* __restrict__ w_ih, const float* __restrict__ lin_w,
    const float* __restrict__ lin_b, const float* __restrict__ b_ih,
    const float* __restrict__ b_hh, float* __restrict__ Wc, float* __restrict__ bc)
{
  __shared__ float sRow[256];
  const int n = blockIdx.x;
  const int j = threadIdx.x;
  sRow[j] = w_ih[n * 256 + j];
  __syncthreads();
  if (j < 132) {
    float acc = 0.f;
    if (j < 129) {
      for (int k = 0; k < 256; ++k) acc += sRow[k] * lin_w[k * 129 + j];
    }
    Wc[n * 132 + j] = acc;
  } else if (j == 255) {
    float acc = b_ih[n] + b_hh[n];
    for (int k = 0; k < 256; ++k) acc += sRow[k] * lin_b[k];
    bc[n] = acc;
  }
}

__global__ __launch_bounds__(256) void transpose_w3(const float* __restrict__ w3,
                                                    float* __restrict__ w3t)
{
  int i = blockIdx.x * 256 + threadIdx.x;
  if (i < 96 * 128) { int s = i >> 7, o = i & 127; w3t[i] = w3[o * 96 + s]; }
}

// K1c: pack Wc into MFMA-A-frag chunks (bf16) + permuted bias
__global__ __launch_bounds__(256) void pack_wc(
    const float* __restrict__ Wc, const float* __restrict__ bc,
    unsigned short* __restrict__ Wcperm, float* __restrict__ bcp)
{
  const int cid = blockIdx.x * 256 + threadIdx.x;
  if (cid >= 64 * 5 * 64) return;
  const int q = cid / 320, rem = cid - q * 320;
  const int o = rem >> 6, l = rem & 63;
  const int m = l >> 2, kg = l & 3;
  const int n = nrow(q, m);
  unsigned short out[8];
  #pragma unroll
  for (int e = 0; e < 8; ++e) {
    const int kz = o * 32 + kg * 8 + e;
    float v = (kz < 129) ? Wc[n * 132 + kz] : (kz == 129 ? Wc[n * 132] : 0.f);
    out[e] = f2bf(v);
  }
  *(ulonglong2*)(Wcperm + cid * 8) = *(ulonglong2*)out;
  if (o == 0 && kg == 0) bcp[q * 16 + m] = bc[n];
}

// K1d: pack w_hh into A-frag chunks: chunk id = ((q*8+o)*16+m)*4+kg
__global__ __launch_bounds__(256) void pack_whh(
    const float* __restrict__ whh, unsigned short* __restrict__ whhp)
{
  const int cid = blockIdx.x * 256 + threadIdx.x;   // < 32768
  const int q = cid >> 9, rem = cid & 511;
  const int o = rem >> 6, l = rem & 63;
  const int m = l >> 2, kg = l & 3;
  const int n = nrow(q, m);
  unsigned short out[8];
  #pragma unroll
  for (int e = 0; e < 8; ++e)
    out[e] = f2bf(whh[n * 256 + o * 32 + kg * 8 + e]);
  *(ulonglong2*)(whhp + cid * 8) = *(ulonglong2*)out;
}

// K2: gather + conv1/conv2/conv3 -> zw[t][b][ZK] bf16 (R7 verbatim).
__global__ __launch_bounds__(64) void conv_kernel(
    const int* __restrict__ alpha, const float* __restrict__ sound,
    const float* __restrict__ w1, const float* __restrict__ b1v,
    const float* __restrict__ w2, const float* __restrict__ b2,
    const float* __restrict__ w3t, const float* __restrict__ b3,
    unsigned short* __restrict__ zw)
{
  __shared__ float win[2048];
  __shared__ float sY2[96];
  const int l = threadIdx.x;
  const int b = blockIdx.x >> 8;
  const int t = blockIdx.x & 255;
  const int a = alpha[b * TLEN + t];
  const int a0 = a - 1024;
  const float* srow = sound + (size_t)b * LSND;
  for (int x = l; x < 2048; x += 64) {
    int p = a0 + x;
    win[x] = (p >= 0 && p < LSND) ? srow[p] : 0.f;
  }
  __syncthreads();
  float acc0 = 0.f, acc1 = 0.f, acc2 = 0.f;
  for (int f = l; f < 2046; f += 64) {
    float wv = w1[f];
    acc0 += win[f] * wv;
    acc1 += win[f + 1] * wv;
    acc2 += win[f + 2] * wv;
  }
  for (int m = 32; m; m >>= 1) {
    acc0 += __shfl_xor(acc0, m);
    acc1 += __shfl_xor(acc1, m);
    acc2 += __shfl_xor(acc2, m);
  }
  const float bb = b1v[0];
  const float y11 = acc0 + bb, y12 = acc1 + bb, y13 = acc2 + bb;
  {
    int s = l;
    int c = s / 3, lp = s - c * 3;
    float wA = w2[c * 3], wB = w2[c * 3 + 1], wC = w2[c * 3 + 2];
    float v = (lp == 0) ? (y11 * wB + y12 * wC)
            : (lp == 1) ? (y11 * wA + y12 * wB + y13 * wC)
                        : (y12 * wA + y13 * wB);
    sY2[s] = fmaxf(v + b2[c], 0.f);
    if (l < 32) {
      s = 64 + l; c = s / 3; lp = s - c * 3;
      wA = w2[c * 3]; wB = w2[c * 3 + 1]; wC = w2[c * 3 + 2];
      v = (lp == 0) ? (y11 * wB + y12 * wC)
        : (lp == 1) ? (y11 * wA + y12 * wB + y13 * wC)
                    : (y12 * wA + y13 * wB);
      sY2[s] = fmaxf(v + b2[c], 0.f);
    }
  }
  __syncthreads();
  float o0 = b3[l], o1 = b3[l + 64];
  for (int s = 0; s < 96; ++s) {
    float yv = sY2[s];
    o0 += yv * w3t[s * 128 + l];
    o1 += yv * w3t[s * 128 + l + 64];
  }
  unsigned short* zrow = zw + ((size_t)t * BSZ + b) * ZK;
  zrow[1 + l] = f2bf(o0);
  zrow[65 + l] = f2bf(o1);
  if (l == 0) {
    int prev = (t > 0) ? alpha[b * TLEN + t - 1] : 0;
    float iv = (float)(a - prev);
    unsigned short hi = f2bf(iv);
    zrow[0] = hi;
    float rec = __uint_as_float(((unsigned)hi) << 16);
    zrow[129] = f2bf(iv - rec);
  }
  if (l < 30) zrow[130 + l] = 0;
}

// K2b: xw GEMM (proven): xw[t][b][n] = z.Wc^T + bc, bf16, frag-linear layout.
__global__ __launch_bounds__(256) void xw_gemm(
    const unsigned short* __restrict__ zw, const unsigned short* __restrict__ Wcperm,
    const float* __restrict__ bcp, unsigned short* __restrict__ xwp)
{
  const int t = (int)blockIdx.x >> 2;
  const int bt = (int)blockIdx.x & 3;
  const int tid = threadIdx.x;
  const int w = tid >> 6, ln = tid & 63;
  const int bl = ln & 15, kg = ln >> 4;

  bf16x8 zf[5];
  #pragma unroll
  for (int o = 0; o < 5; ++o)
    zf[o] = *(const bf16x8*)(zw + ((size_t)t * BSZ + (bt << 4) + bl) * ZK + o * 32 + kg * 8);

  #pragma unroll 2
  for (int qq = 0; qq < 16; ++qq) {
    const int q = (w << 4) + qq;
    f32x4 acc = *(const f32x4*)(bcp + q * 16 + (kg << 2));
    #pragma unroll
    for (int o = 0; o < 5; ++o) {
      bf16x8 af = *(const bf16x8*)(Wcperm + ((size_t)(q * 5 + o) * 64 + (bl << 2) + kg) * 8);
      acc = __builtin_amdgcn_mfma_f32_16x16x32_bf16(af, zf[o], acc, 0, 0, 0);
    }
    uint2 pk;
    pk.x = (unsigned)f2bf(acc[0]) | ((unsigned)f2bf(acc[1]) << 16);
    pk.y = (unsigned)f2bf(acc[2]) | ((unsigned)f2bf(acc[3]) << 16);
    char* dst = (char*)xwp + (((size_t)t * 4 + bt) << 15)
              + ((q * 32 + bl * 2 + (kg >> 1)) << 4) + ((kg & 1) << 3);
    *(uint2*)dst = pk;
  }
}

// K3: pairwise MFMA LSTM, RTT-overlapped schedule. 8 blocks (bt x jh) x 512 thr.
// Per step: [A] own-half MFMA (K=128, block-local LDS) + issue xw(t+1) prefetch;
// [B] poll partner's 128 j (u32 mailboxes {bf16<<16 | tag16}, agent-scope relaxed,
// payload rides the load, bounded) -> LDS; barrier; [C] partner-half MFMA;
// [D] gates -> publish u32 stores (streamed per q) + own h -> LDS; barrier.
// Own-half MFMA and xw prefetch hide inside the partner RTT. 2-buffer rotation
// (pairwise-causal safe, R10 argument).
__global__ void __launch_bounds__(512, 1) lstm_kernel(
    const unsigned short* __restrict__ whhp, const unsigned short* __restrict__ xwp,
    unsigned* __restrict__ hq, float* __restrict__ hfin)
{
  __shared__ unsigned short sH[2][16][256];   // [parity][b][j], 16B-slot XOR swizzle
  char* sHb = (char*)sH;

  const int tid = threadIdx.x;
  const int w = tid >> 6, ln = tid & 63;
  const int bl = ln & 15, kg = ln >> 4;
  const int bid = (int)blockIdx.x;            // 0..7
  const int bt = bid >> 1, jh = bid & 1;
  const int b = (bt << 4) + bl;
  const int oOwn = jh << 2;                   // own o-frags [oOwn, oOwn+4)
  const int oPar = (jh ^ 1) << 2;             // partner o-frags
  const int pb = (jh ^ 1) << 7;               // partner j-base

  // ---- weights: 4 q-tiles x 8 k-frags, register/AGPR-resident ----
  bf16x8 wfr[4][8];
  #pragma unroll
  for (int q = 0; q < 4; ++q) {
    const int qg = (jh << 5) + (w << 2) + q;
    #pragma unroll
    for (int o = 0; o < 8; ++o)
      wfr[q][o] = *(const bf16x8*)(whhp + (((size_t)(qg * 8 + o) * 16 + bl) * 4 + kg) * 8);
  }

  // zero both LDS parities (h(0) = 0)
  for (int i = tid; i < 4096; i += 512) ((unsigned*)sHb)[i] = 0;

  // poll role: row = tid>>5 (local b), pj0 = (tid&31)*4 (partner-local j)
  const int prow = tid >> 5;
  const int pj0 = (tid & 31) << 2;
  const unsigned pollidx = (unsigned)(prow * 128 + pj0);
  char* pdst = sHb + (prow << 9) + ((((pb + pj0) >> 3) ^ prow) << 4) + ((pj0 & 7) << 1);

  // xw registers: cur = t, nxt = t+1 (prefetched during phase A)
  unsigned long long xcur[4], xnxt[4];
  {
    const char* xb = (const char*)xwp + (((size_t)0 * 4 + bt) << 15) + ((kg & 1) << 3);
    #pragma unroll
    for (int q = 0; q < 4; ++q) {
      const int chunk = (((jh << 5) + (w << 2) + q) << 5) + (bl << 1) + (kg >> 1);
      xcur[q] = *(const unsigned long long*)(xb + (chunk << 4));
    }
  }
  float cs[4] = {0.f, 0.f, 0.f, 0.f};
  __syncthreads();

  #pragma unroll 1
  for (int t = 0; t < TLEN; ++t) {
    const int p_ = (t & 1) << 13;

    // ---- [A] own-half MFMA + xw(t+1) prefetch issue ----
    f32x4 acc[4];
    {
      bf16x8 hfo[4];
      #pragma unroll
      for (int o = 0; o < 4; ++o)
        hfo[o] = *(const bf16x8*)(sHb + p_ + (bl << 9)
                                  + (((((oOwn + o) << 2) + kg) ^ bl) << 4));
      #pragma unroll
      for (int q = 0; q < 4; ++q) {
        acc[q] = unpack4(xcur[q]);
        #pragma unroll
        for (int o = 0; o < 4; ++o)
          acc[q] = __builtin_amdgcn_mfma_f32_16x16x32_bf16(wfr[q][oOwn + o], hfo[o],
                                                           acc[q], 0, 0, 0);
      }
    }
    if (t + 1 < TLEN) {
      const char* xb = (const char*)xwp + (((size_t)(t + 1) * 4 + bt) << 15) + ((kg & 1) << 3);
      #pragma unroll
      for (int q = 0; q < 4; ++q) {
        const int chunk = (((jh << 5) + (w << 2) + q) << 5) + (bl << 1) + (kg >> 1);
        xnxt[q] = *(const unsigned long long*)(xb + (chunk << 4));
      }
    }

    // ---- [B] poll partner h(t): 4 u32 tagged words; payload rides the load ----
    if (t > 0) {
      const unsigned* hs = hq + ((size_t)(t & 1)) * 16384
                         + ((size_t)(bid ^ 1) << 11) + pollidx;
      const unsigned tagw = (unsigned)t & 0xFFFFu;
      unsigned v0 = __hip_atomic_load(hs + 0, __ATOMIC_RELAXED, __HIP_MEMORY_SCOPE_AGENT);
      unsigned v1 = __hip_atomic_load(hs + 1, __ATOMIC_RELAXED, __HIP_MEMORY_SCOPE_AGENT);
      unsigned v2 = __hip_atomic_load(hs + 2, __ATOMIC_RELAXED, __HIP_MEMORY_SCOPE_AGENT);
      unsigned v3 = __hip_atomic_load(hs + 3, __ATOMIC_RELAXED, __HIP_MEMORY_SCOPE_AGENT);
      int guard = 0;
      for (;;) {
        bool ok = true;
        if ((v0 & 0xFFFFu) != tagw) {
          v0 = __hip_atomic_load(hs + 0, __ATOMIC_RELAXED, __HIP_MEMORY_SCOPE_AGENT); ok = false; }
        if ((v1 & 0xFFFFu) != tagw) {
          v1 = __hip_atomic_load(hs + 1, __ATOMIC_RELAXED, __HIP_MEMORY_SCOPE_AGENT); ok = false; }
        if ((v2 & 0xFFFFu) != tagw) {
          v2 = __hip_atomic_load(hs + 2, __ATOMIC_RELAXED, __HIP_MEMORY_SCOPE_AGENT); ok = false; }
        if ((v3 & 0xFFFFu) != tagw) {
          v3 = __hip_atomic_load(hs + 3, __ATOMIC_RELAXED, __HIP_MEMORY_SCOPE_AGENT); ok = false; }
        if (ok || ++guard > (1 << 20)) break;
      }
      unsigned long long pay =
          (unsigned long long)(v0 >> 16)
        | ((unsigned long long)(v1 >> 16) << 16)
        | ((unsigned long long)(v2 >> 16) << 32)
        | ((unsigned long long)(v3 >> 16) << 48);
      *(unsigned long long*)(pdst + p_) = pay;   // 4 partner j's into LDS
    }
    __syncthreads();

    // ---- [C] partner-half MFMA ----
    {
      bf16x8 hfp[4];
      #pragma unroll
      for (int o = 0; o < 4; ++o)
        hfp[o] = *(const bf16x8*)(sHb + p_ + (bl << 9)
                                  + (((((oPar + o) << 2) + kg) ^ bl) << 4));
      #pragma unroll
      for (int q = 0; q < 4; ++q) {
        #pragma unroll
        for (int o = 0; o < 4; ++o)
          acc[q] = __builtin_amdgcn_mfma_f32_16x16x32_bf16(wfr[q][oPar + o], hfp[o],
                                                           acc[q], 0, 0, 0);
      }
    }

    // ---- [D] gates -> publish (streamed per q) + own h -> LDS ----
    #pragma unroll
    for (int q = 0; q < 4; ++q) {
      cs[q] = sigm(acc[q][1]) * cs[q] + sigm(acc[q][0]) * tanh_f(acc[q][2]);
      const float hv = sigm(acc[q][3]) * tanh_f(cs[q]);
      const int jloc = (w << 4) + (q << 2) + kg;
      const int jglob = (jh << 7) + jloc;
      if (t < TLEN - 1) {
        const unsigned short hb = f2bf(hv);
        // publish to partner immediately (fire-and-forget)
        const unsigned pk = ((unsigned)hb << 16) | ((unsigned)(t + 1) & 0xFFFFu);
        __hip_atomic_store(hq + ((size_t)((t + 1) & 1)) * 16384 + ((size_t)bid << 11)
                               + (bl << 7) + jloc,
                           pk, __ATOMIC_RELAXED, __HIP_MEMORY_SCOPE_AGENT);
        // own half -> LDS parity^1
        *(unsigned short*)(sHb + (p_ ^ 8192) + (bl << 9)
                           + (((jglob >> 3) ^ bl) << 4) + ((jglob & 7) << 1)) = hb;
      } else {
        hfin[b * 256 + jglob] = hv;
      }
    }
    #pragma unroll
    for (int q = 0; q < 4; ++q) xcur[q] = xnxt[q];
    __syncthreads();
  }
}

// K4: head
__global__ __launch_bounds__(256) void head_kernel(
    const float* __restrict__ hfin, const float* __restrict__ o1w,
    const float* __restrict__ o1b, const float* __restrict__ o2w,
    const float* __restrict__ o2b, float* __restrict__ out)
{
  __shared__ float sR[32];
  const int b = blockIdx.x;
  const int tid = threadIdx.x;
  const int m = tid >> 3, g = tid & 7;
  const float* h = hfin + b * 256;
  float acc = 0.f;
  for (int k = g * 32; k < g * 32 + 32; ++k) acc += h[k] * o1w[m * 256 + k];
  acc += __shfl_xor(acc, 1); acc += __shfl_xor(acc, 2); acc += __shfl_xor(acc, 4);
  if (g == 0) sR[m] = fmaxf(acc + o1b[m], 0.f);
  __syncthreads();
  if (tid == 0) {
    float s = o2b[0];
    for (int mm = 0; mm < 32; ++mm) s += sR[mm] * o2w[mm];
    out[b] = sigm(s);
  }
}

extern "C" void kernel_launch(void* const* d_in, const int* in_sizes, int n_in,
                              void* d_out, int out_size, void* d_ws, size_t ws_size,
                              hipStream_t stream) {
  (void)in_sizes; (void)n_in; (void)out_size; (void)ws_size;
  const int*   alpha = (const int*)  d_in[0];
  const float* sound = (const float*)d_in[1];
  const float* w1    = (const float*)d_in[2];
  const float* b1    = (const float*)d_in[3];
  const float* w2    = (const float*)d_in[4];
  const float* b2    = (const float*)d_in[5];
  const float* w3    = (const float*)d_in[6];
  const float* b3    = (const float*)d_in[7];
  const float* linw  = (const float*)d_in[8];
  const float* linb  = (const float*)d_in[9];
  const float* wih   = (const float*)d_in[10];
  const float* whh   = (const float*)d_in[11];
  const float* bih   = (const float*)d_in[12];
  const float* bhh   = (const float*)d_in[13];
  const float* o1w   = (const float*)d_in[14];
  const float* o1b   = (const float*)d_in[15];
  const float* o2w   = (const float*)d_in[16];
  const float* o2b   = (const float*)d_in[17];

  // byte layout (16B-aligned). hq reuses the Wcperm region: memset AFTER xw_gemm
  // (stream-ordered), since Wcperm/bcp are dead once xw_gemm completes.
  char* p = (char*)d_ws;
  unsigned short* zw     = (unsigned short*)p;              // 5,242,880 B
  float*          Wc     = (float*)(p + 5242880);           //   540,672 B
  float*          bc     = (float*)(p + 5783552);           //     4,096 B
  float*          w3t    = (float*)(p + 5787648);           //    49,152 B
  float*          hfin   = (float*)(p + 5836800);           //    65,536 B
  unsigned short* Wcperm = (unsigned short*)(p + 5902336);  //   327,680 B (later: hq)
  float*          bcp    = (float*)(p + 6230016);           //     4,096 B
  unsigned short* whhp   = (unsigned short*)(p + 6234112);  //   524,288 B
  unsigned short* xwp    = (unsigned short*)(p + 6758400);  // 33,554,432 B -> 40,312,832
  unsigned*       hq     = (unsigned*)(p + 5902336);        // 2*8*2048 u32 = 131,072 B

  prep_kernel<<<1024, 256, 0, stream>>>(wih, linw, linb, bih, bhh, Wc, bc);
  transpose_w3<<<48, 256, 0, stream>>>(w3, w3t);
  conv_kernel<<<BSZ * TLEN, 64, 0, stream>>>(alpha, sound, w1, b1, w2, b2, w3t, b3, zw);
  pack_wc<<<80, 256, 0, stream>>>(Wc, bc, Wcperm, bcp);
  pack_whh<<<128, 256, 0, stream>>>(whh, whhp);
  xw_gemm<<<TLEN * 4, 256, 0, stream>>>(zw, Wcperm, bcp, xwp);
  hipMemsetAsync(hq, 0, 131072, stream);      // tags=0 (Wcperm dead from here)
  lstm_kernel<<<8, 512, 0, stream>>>(whhp, xwp, hq, hfin);
  head_kernel<<<BSZ, 256, 0, stream>>>(hfin, o1w, o1b, o2w, o2b, (float*)d_out);
}